// Round 1
// baseline (530.301 us; speedup 1.0000x reference)
//
#include <hip/hip_runtime.h>
#include <stdint.h>

typedef __bf16 bf16x8 __attribute__((ext_vector_type(8)));
typedef float f32x4 __attribute__((ext_vector_type(4)));
typedef unsigned short u16x8 __attribute__((ext_vector_type(8)));
typedef unsigned int u32x4 __attribute__((ext_vector_type(4)));

__device__ __forceinline__ unsigned short f2bf(float f) {
    unsigned int u = __builtin_bit_cast(unsigned int, f);
    unsigned int r = u + 0x7fffu + ((u >> 16) & 1u);
    return (unsigned short)(r >> 16);
}

// v_cvt_pk_bf16_f32: lo <- bf16(a), hi <- bf16(b)
__device__ __forceinline__ unsigned int cvt_pk_bf16(float a, float b) {
    unsigned int r;
    asm("v_cvt_pk_bf16_f32 %0, %1, %2" : "=v"(r) : "v"(a), "v"(b));
    return r;
}

// async global->LDS, 16B per lane. LDS dest = wave-uniform base + lane*16.
__device__ __forceinline__ void async16(const void* g, void* l) {
    __builtin_amdgcn_global_load_lds(
        (const __attribute__((address_space(1))) void*)g,
        (__attribute__((address_space(3))) void*)l, 16, 0, 0);
}

// ---------------------------------------------------------------------------
// x fp32 -> bf16, elementwise (8 elems/thread)
// ---------------------------------------------------------------------------
__global__ __launch_bounds__(256) void cast_bf16(
    const float* __restrict__ src, unsigned short* __restrict__ dst, int n8)
{
    int i = blockIdx.x * 256 + threadIdx.x;
    if (i >= n8) return;
    const float* f = src + (size_t)i * 8;
    f32x4 a = *reinterpret_cast<const f32x4*>(f);
    f32x4 b = *reinterpret_cast<const f32x4*>(f + 4);
    u16x8 r;
    r[0]=f2bf(a[0]); r[1]=f2bf(a[1]); r[2]=f2bf(a[2]); r[3]=f2bf(a[3]);
    r[4]=f2bf(b[0]); r[5]=f2bf(b[1]); r[6]=f2bf(b[2]); r[7]=f2bf(b[3]);
    *reinterpret_cast<u16x8*>(dst + (size_t)i * 8) = r;
}

// ---------------------------------------------------------------------------
// W fp32 [R][Cc] -> bf16 W^T [Cc][R]. 64x64 tiles, XOR-swizzled LDS
// ---------------------------------------------------------------------------
__global__ __launch_bounds__(256) void transpose_cast_f32(
    const float* __restrict__ src, unsigned short* __restrict__ dst, int R, int Cc)
{
    __shared__ unsigned short St[64 * 64];
    const int tid = threadIdx.x;
    const int r0 = blockIdx.y * 64, c0 = blockIdx.x * 64;
    const int lr  = tid >> 2;          // 0..63
    const int lcb = (tid & 3) * 16;    // 0,16,32,48
    const float* sp = src + (size_t)(r0 + lr) * Cc + c0 + lcb;
    #pragma unroll
    for (int u = 0; u < 4; u++) {
        f32x4 v = *reinterpret_cast<const f32x4*>(sp + 4 * u);
        #pragma unroll
        for (int e = 0; e < 4; e++) {
            int c = lcb + 4 * u + e;
            St[c * 64 + (((lr >> 3) ^ ((c >> 4) & 3)) << 3) + (lr & 7)] = f2bf(v[e]);
        }
    }
    __syncthreads();
    #pragma unroll
    for (int i = 0; i < 2; i++) {
        int ck = tid + 256 * i;
        int c = ck >> 3, ch = ck & 7;
        u16x8 val = *reinterpret_cast<const u16x8*>(&St[c * 64 + ((ch ^ ((c >> 4) & 3)) << 3)]);
        *reinterpret_cast<u16x8*>(dst + (size_t)(c0 + c) * R + r0 + ch * 8) = val;
    }
}

// ---------------------------------------------------------------------------
// V-part of qkv [b,t,4096+h*128+d] (bf16) -> VT [b][h][d][t'] (bf16), where
// within each 32-t block, t' is PERMUTED so flash's PV contraction-index
// order matches the swapped-QK^T P layout:
//   chunk ch (8 elems) = {32*(ch>>2) + 4*(ch&3) + 0..3,
//                         32*(ch>>2) + 16 + 4*(ch&3) + 0..3}
// (a permutation of the contraction axis applied to both P and V — legal.)
// ---------------------------------------------------------------------------
__global__ __launch_bounds__(256) void vtrans(
    const unsigned short* __restrict__ qkv, unsigned short* __restrict__ VT)
{
    const int T = 2048, CH = 6144;
    __shared__ unsigned short St[64 * 64];
    const int tid = threadIdx.x;
    const int bh = blockIdx.z;
    const int b = bh >> 4, h = bh & 15;
    const int t0 = blockIdx.x * 64, d0 = blockIdx.y * 64;
    const int lr  = tid >> 2;
    const int lcb = (tid & 3) * 16;
    const unsigned short* sp = qkv + (size_t)(b * T + t0 + lr) * CH + 4096 + h * 128 + d0 + lcb;
    u16x8 v0 = *reinterpret_cast<const u16x8*>(sp);
    u16x8 v1 = *reinterpret_cast<const u16x8*>(sp + 8);
    #pragma unroll
    for (int e = 0; e < 8; e++) {
        int c = lcb + e;
        St[c * 64 + (((lr >> 3) ^ ((c >> 4) & 3)) << 3) + (lr & 7)] = v0[e];
        c = lcb + 8 + e;
        St[c * 64 + (((lr >> 3) ^ ((c >> 4) & 3)) << 3) + (lr & 7)] = v1[e];
    }
    __syncthreads();
    #pragma unroll
    for (int i = 0; i < 2; i++) {
        int ck = tid + 256 * i;
        int d = ck >> 3, ch = ck & 7;
        const int Q = ch & 3, B32 = ch >> 2;
        u16x8 val;
        #pragma unroll
        for (int e = 0; e < 4; e++) {
            int ta = 32 * B32 + 4 * Q + e;        // first half of chunk
            int tb = ta + 16;                     // second half
            val[e]     = St[d * 64 + (((ta >> 3) ^ ((d >> 4) & 3)) << 3) + (ta & 7)];
            val[4 + e] = St[d * 64 + (((tb >> 3) ^ ((d >> 4) & 3)) << 3) + (tb & 7)];
        }
        *reinterpret_cast<u16x8*>(VT + (size_t)(bh * 128 + d0 + d) * T + t0 + ch * 8) = val;
    }
}

// ---------------------------------------------------------------------------
// m97-style GEMM: C[M,N] = A[M,K] @ BT[N,K]^T, bf16 in, fp32 acc.
// ---------------------------------------------------------------------------
__global__ __launch_bounds__(256) void gemm_bt(
    const unsigned short* __restrict__ A,   // [M][K] bf16
    const unsigned short* __restrict__ BT,  // [N][K] bf16
    void* __restrict__ C, int M, int N, int K, int cF32)
{
    __shared__ unsigned short As[128 * 32];
    __shared__ unsigned short Bs[128 * 32];
    const int tid = threadIdx.x;
    const int w = tid >> 6, lane = tid & 63;
    const int quad = lane >> 4, l16 = lane & 15;
    const int wm = (w >> 1) * 64, wn = (w & 1) * 64;
    const int m0 = blockIdx.y * 128, n0 = blockIdx.x * 128;

    const int srow = w * 16 + (lane >> 2);
    const int scol = (lane & 3) * 8;
    const unsigned short* aG = A  + (size_t)(m0 + srow) * K + scol;
    const unsigned short* bG = BT + (size_t)(n0 + srow) * K + scol;
    unsigned short* aL = As + (w * 16) * 32;
    unsigned short* bL = Bs + (w * 16) * 32;

    f32x4 acc[4][4] = {};

    for (int k0 = 0; k0 < K; k0 += 32) {
        async16(aG + k0, aL);
        async16(aG + (size_t)64 * K + k0, aL + 64 * 32);
        async16(bG + k0, bL);
        async16(bG + (size_t)64 * K + k0, bL + 64 * 32);
        __syncthreads();

        bf16x8 af[4], bf[4];
        #pragma unroll
        for (int i = 0; i < 4; i++)
            af[i] = *reinterpret_cast<const bf16x8*>(&As[(wm + i * 16 + l16) * 32 + quad * 8]);
        #pragma unroll
        for (int c = 0; c < 4; c++)
            bf[c] = *reinterpret_cast<const bf16x8*>(&Bs[(wn + c * 16 + l16) * 32 + quad * 8]);
        #pragma unroll
        for (int i = 0; i < 4; i++)
            #pragma unroll
            for (int c = 0; c < 4; c++)
                acc[i][c] = __builtin_amdgcn_mfma_f32_16x16x32_bf16(af[i], bf[c], acc[i][c], 0, 0, 0);
        __syncthreads();
    }

    #pragma unroll
    for (int i = 0; i < 4; i++)
        #pragma unroll
        for (int c = 0; c < 4; c++)
            #pragma unroll
            for (int r = 0; r < 4; r++) {
                const int row = m0 + wm + i * 16 + quad * 4 + r;
                const int col = n0 + wn + c * 16 + l16;
                const size_t off = (size_t)row * N + col;
                if (cF32) ((float*)C)[off] = acc[i][c][r];
                else ((unsigned short*)C)[off] = f2bf(acc[i][c][r]);
            }
}

// ---------------------------------------------------------------------------
// Flash attention v2 (causal), swapped-QK^T / lane-local softmax.
// Q-tile 128 (4 waves x 2 strips of 16 q-rows), KV-tile 64.
// S^T = mfma(K, Q): lane (quad,l16) holds S[q=qs+l16][kv=nt*16+quad*4+r]
// -> row max/sum = in-register tree + 2 shfl_xor (16,32).
// P packed to bf16 with v_cvt_pk_bf16_f32; PV uses the permuted-k V layout
// (see vtrans) so pf needs NO cross-lane exchange and NO LDS round-trip.
// Defer-max (THR=8, exp2 units) skips the O-rescale on most tiles.
// ---------------------------------------------------------------------------
__global__ __launch_bounds__(256, 3) void flash_attn(
    const unsigned short* __restrict__ qkv,
    const unsigned short* __restrict__ VT,
    unsigned short* __restrict__ Out)
{
    const int T = 2048, CH = 6144;
    __shared__ unsigned short Ks[64 * 128];   // [kv][d-chunk swizzled]
    __shared__ unsigned short Vt[128 * 64];   // [d][kv'-chunk swizzled]

    const int tid = threadIdx.x;
    const int w = tid >> 6, lane = tid & 63;
    const int quad = lane >> 4, l16 = lane & 15;
    const int bh = blockIdx.y, b = bh >> 4, h = bh & 15;
    const int q0 = (gridDim.x - 1 - blockIdx.x) * 128;   // heavy blocks first

    const float sc = 0.08838834764831845f * 1.4426950408889634f;
    const float NINF = -__builtin_inff();

    // Q fragments (B-operand), scale folded in: lane holds sc*Q[qs+l16][dc*32+quad*8+j]
    bf16x8 qf[2][4];
    #pragma unroll
    for (int st = 0; st < 2; st++) {
        const unsigned short* qrow = qkv + (size_t)(b * T + q0 + w * 32 + st * 16 + l16) * CH + h * 128;
        #pragma unroll
        for (int dc = 0; dc < 4; dc++) {
            u16x8 raw = *reinterpret_cast<const u16x8*>(qrow + dc * 32 + quad * 8);
            u16x8 scl;
            #pragma unroll
            for (int e = 0; e < 8; e++) {
                float f = __builtin_bit_cast(float, (unsigned int)raw[e] << 16);
                scl[e] = f2bf(f * sc);
            }
            qf[st][dc] = __builtin_bit_cast(bf16x8, scl);
        }
    }

    f32x4 o[2][8] = {};
    float m_i[2] = {NINF, NINF};
    float l_i[2] = {0.f, 0.f};
    const int xsw = l16 & 7;

    for (int kv0 = 0; kv0 < q0 + 128; kv0 += 64) {
        // ---- stage K tile (64 kv x 128 d), chunk-swizzled on the global side ----
        #pragma unroll
        for (int i = 0; i < 4; i++) {
            const int r0 = i * 16 + w * 4;
            const int kv = r0 + (lane >> 4);
            const int ch = (lane & 15) ^ (kv & 7);
            async16(qkv + (size_t)(b * T + kv0 + kv) * CH + 2048 + h * 128 + ch * 8,
                    Ks + r0 * 128);
        }
        // ---- stage V'^T tile (128 d x 64 kv', already k-permuted in VT) ----
        #pragma unroll
        for (int i = 0; i < 4; i++) {
            const int r0 = i * 32 + w * 8;
            const int d = r0 + (lane >> 3);
            const int ch = (lane & 7) ^ (d & 7);
            async16(VT + ((size_t)bh * 128 + d) * T + kv0 + ch * 8,
                    Vt + r0 * 64);
        }
        __syncthreads();

        // ---- S^T = K Q^T : s[st][nt][r] = S[q=qs+l16][kv0 + nt*16 + quad*4 + r] ----
        f32x4 s[2][4] = {};
        #pragma unroll
        for (int dc = 0; dc < 4; dc++)
            #pragma unroll
            for (int nt = 0; nt < 4; nt++) {
                bf16x8 kf = *reinterpret_cast<const bf16x8*>(
                    &Ks[(nt * 16 + l16) * 128 + (((dc * 4 + quad) ^ xsw) << 3)]);
                s[0][nt] = __builtin_amdgcn_mfma_f32_16x16x32_bf16(kf, qf[0][dc], s[0][nt], 0, 0, 0);
                s[1][nt] = __builtin_amdgcn_mfma_f32_16x16x32_bf16(kf, qf[1][dc], s[1][nt], 0, 0, 0);
            }

        // ---- softmax, lane-local rows ----
        unsigned int pk[2][4][2];
        #pragma unroll
        for (int st = 0; st < 2; st++) {
            const int qs = q0 + w * 32 + st * 16;
            const int qrow = qs + l16;
            if (kv0 + 63 > qs) {                     // diagonal: apply causal mask
                #pragma unroll
                for (int nt = 0; nt < 4; nt++)
                    #pragma unroll
                    for (int r = 0; r < 4; r++)
                        if (kv0 + nt * 16 + quad * 4 + r > qrow) s[st][nt][r] = NINF;
            }
            // row max over 16 in-register + 2 shuffles across quads
            float mx = fmaxf(fmaxf(fmaxf(s[st][0][0], s[st][0][1]), fmaxf(s[st][0][2], s[st][0][3])),
                             fmaxf(fmaxf(s[st][1][0], s[st][1][1]), fmaxf(s[st][1][2], s[st][1][3])));
            mx = fmaxf(mx,
                 fmaxf(fmaxf(fmaxf(s[st][2][0], s[st][2][1]), fmaxf(s[st][2][2], s[st][2][3])),
                       fmaxf(fmaxf(s[st][3][0], s[st][3][1]), fmaxf(s[st][3][2], s[st][3][3]))));
            mx = fmaxf(mx, __shfl_xor(mx, 16));
            mx = fmaxf(mx, __shfl_xor(mx, 32));

            const float mold = m_i[st];
            if (!__all(mx <= mold + 8.0f)) {         // rescale (rare after tile 0)
                const float mnew = fmaxf(mold, mx);
                const float alpha = exp2f(mold - mnew);
                m_i[st] = mnew;
                l_i[st] *= alpha;
                #pragma unroll
                for (int r = 0; r < 4; r++) {
                    const float a = __shfl(alpha, quad * 4 + r);
                    #pragma unroll
                    for (int c = 0; c < 8; c++) o[st][c][r] *= a;
                }
            }
            const float m = m_i[st];
            float p[4][4];
            #pragma unroll
            for (int nt = 0; nt < 4; nt++)
                #pragma unroll
                for (int r = 0; r < 4; r++)
                    p[nt][r] = exp2f(s[st][nt][r] - m);
            float ps = ((p[0][0] + p[0][1]) + (p[0][2] + p[0][3]))
                     + ((p[1][0] + p[1][1]) + (p[1][2] + p[1][3]))
                     + ((p[2][0] + p[2][1]) + (p[2][2] + p[2][3]))
                     + ((p[3][0] + p[3][1]) + (p[3][2] + p[3][3]));
            ps += __shfl_xor(ps, 16);
            ps += __shfl_xor(ps, 32);
            l_i[st] += ps;
            #pragma unroll
            for (int nt = 0; nt < 4; nt++) {
                pk[st][nt][0] = cvt_pk_bf16(p[nt][0], p[nt][1]);
                pk[st][nt][1] = cvt_pk_bf16(p[nt][2], p[nt][3]);
            }
        }

        // ---- O += P V : pf comes straight from pk (permuted-k, no exchange) ----
        #pragma unroll
        for (int kc = 0; kc < 2; kc++) {
            u32x4 a0, a1;
            a0[0] = pk[0][2*kc][0]; a0[1] = pk[0][2*kc][1];
            a0[2] = pk[0][2*kc+1][0]; a0[3] = pk[0][2*kc+1][1];
            a1[0] = pk[1][2*kc][0]; a1[1] = pk[1][2*kc][1];
            a1[2] = pk[1][2*kc+1][0]; a1[3] = pk[1][2*kc+1][1];
            const bf16x8 pf0 = __builtin_bit_cast(bf16x8, a0);
            const bf16x8 pf1 = __builtin_bit_cast(bf16x8, a1);
            #pragma unroll
            for (int c = 0; c < 8; c++) {
                bf16x8 vf = *reinterpret_cast<const bf16x8*>(
                    &Vt[(c * 16 + l16) * 64 + (((kc * 4 + quad) ^ xsw) << 3)]);
                o[0][c] = __builtin_amdgcn_mfma_f32_16x16x32_bf16(pf0, vf, o[0][c], 0, 0, 0);
                o[1][c] = __builtin_amdgcn_mfma_f32_16x16x32_bf16(pf1, vf, o[1][c], 0, 0, 0);
            }
        }
        __syncthreads();
    }

    #pragma unroll
    for (int st = 0; st < 2; st++)
        #pragma unroll
        for (int r = 0; r < 4; r++) {
            const float linv = 1.0f / __shfl(l_i[st], quad * 4 + r);
            const int row = q0 + w * 32 + st * 16 + quad * 4 + r;
            const size_t base = (size_t)(b * T + row) * 2048 + h * 128;
            #pragma unroll
            for (int c = 0; c < 8; c++)
                Out[base + c * 16 + l16] = f2bf(o[st][c][r] * linv);
        }
}

extern "C" void kernel_launch(void* const* d_in, const int* in_sizes, int n_in,
                              void* d_out, int out_size, void* d_ws, size_t ws_size,
                              hipStream_t stream) {
    const int B = 2, T = 2048, C = 2048;
    const float* x    = (const float*)d_in[0];
    const float* Wqkv = (const float*)d_in[2];   // [C][3C] fp32
    const float* Wout = (const float*)d_in[3];   // [C][C]  fp32
    const int M = B * T;                         // 4096

    char* ws = (char*)d_ws;
    unsigned short* qkv   = (unsigned short*)ws;                       // +0
    unsigned short* xb    = (unsigned short*)(ws + 50331648);          // region A
    unsigned short* WoutT = xb;
    unsigned short* WqkvT = (unsigned short*)(ws + 67108864);          // region B
    unsigned short* VTp   = WqkvT;
    unsigned short* O     = (unsigned short*)(ws + 92274688);

    // 1) casts for GEMM1
    cast_bf16<<<dim3(M * C / 8 / 256), 256, 0, stream>>>(x, xb, M * C / 8);
    transpose_cast_f32<<<dim3(3 * C / 64, C / 64), 256, 0, stream>>>(Wqkv, WqkvT, C, 3 * C);
    // 2) qkv = xb @ WqkvT^T
    gemm_bt<<<dim3(3 * C / 128, M / 128), 256, 0, stream>>>(xb, WqkvT, qkv, M, 3 * C, C, 0);
    // 3) V transpose (k-permuted layout) and Wout cast
    vtrans<<<dim3(T / 64, 2, B * 16), 256, 0, stream>>>(qkv, VTp);
    transpose_cast_f32<<<dim3(C / 64, C / 64), 256, 0, stream>>>(Wout, WoutT, C, C);
    // 4) flash attention
    flash_attn<<<dim3(T / 128, B * 16), 256, 0, stream>>>(qkv, VTp, O);
    // 5) out = O @ WoutT^T (fp32 out)
    gemm_bt<<<dim3(C / 128, M / 128), 256, 0, stream>>>(O, WoutT, d_out, M, C, C, 1);
}

// Round 2
// 451.756 us; speedup vs baseline: 1.1739x; 1.1739x over previous
//
#include <hip/hip_runtime.h>
#include <stdint.h>

typedef __bf16 bf16x8 __attribute__((ext_vector_type(8)));
typedef float f32x4 __attribute__((ext_vector_type(4)));
typedef unsigned short u16x8 __attribute__((ext_vector_type(8)));
typedef unsigned int u32x4 __attribute__((ext_vector_type(4)));

__device__ __forceinline__ unsigned short f2bf(float f) {
    unsigned int u = __builtin_bit_cast(unsigned int, f);
    unsigned int r = u + 0x7fffu + ((u >> 16) & 1u);
    return (unsigned short)(r >> 16);
}

// v_cvt_pk_bf16_f32: lo <- bf16(a), hi <- bf16(b)
__device__ __forceinline__ unsigned int cvt_pk_bf16(float a, float b) {
    unsigned int r;
    asm("v_cvt_pk_bf16_f32 %0, %1, %2" : "=v"(r) : "v"(a), "v"(b));
    return r;
}

// async global->LDS, 16B per lane. LDS dest = wave-uniform base + lane*16.
__device__ __forceinline__ void async16(const void* g, void* l) {
    __builtin_amdgcn_global_load_lds(
        (const __attribute__((address_space(1))) void*)g,
        (__attribute__((address_space(3))) void*)l, 16, 0, 0);
}

// ---------------------------------------------------------------------------
// x fp32 -> bf16, elementwise (8 elems/thread)
// ---------------------------------------------------------------------------
__global__ __launch_bounds__(256) void cast_bf16(
    const float* __restrict__ src, unsigned short* __restrict__ dst, int n8)
{
    int i = blockIdx.x * 256 + threadIdx.x;
    if (i >= n8) return;
    const float* f = src + (size_t)i * 8;
    f32x4 a = *reinterpret_cast<const f32x4*>(f);
    f32x4 b = *reinterpret_cast<const f32x4*>(f + 4);
    u16x8 r;
    r[0]=f2bf(a[0]); r[1]=f2bf(a[1]); r[2]=f2bf(a[2]); r[3]=f2bf(a[3]);
    r[4]=f2bf(b[0]); r[5]=f2bf(b[1]); r[6]=f2bf(b[2]); r[7]=f2bf(b[3]);
    *reinterpret_cast<u16x8*>(dst + (size_t)i * 8) = r;
}

// ---------------------------------------------------------------------------
// W fp32 [R][Cc] -> bf16 W^T [Cc][R]. 64x64 tiles, XOR-swizzled LDS
// ---------------------------------------------------------------------------
__global__ __launch_bounds__(256) void transpose_cast_f32(
    const float* __restrict__ src, unsigned short* __restrict__ dst, int R, int Cc)
{
    __shared__ unsigned short St[64 * 64];
    const int tid = threadIdx.x;
    const int r0 = blockIdx.y * 64, c0 = blockIdx.x * 64;
    const int lr  = tid >> 2;          // 0..63
    const int lcb = (tid & 3) * 16;    // 0,16,32,48
    const float* sp = src + (size_t)(r0 + lr) * Cc + c0 + lcb;
    #pragma unroll
    for (int u = 0; u < 4; u++) {
        f32x4 v = *reinterpret_cast<const f32x4*>(sp + 4 * u);
        #pragma unroll
        for (int e = 0; e < 4; e++) {
            int c = lcb + 4 * u + e;
            St[c * 64 + (((lr >> 3) ^ ((c >> 4) & 3)) << 3) + (lr & 7)] = f2bf(v[e]);
        }
    }
    __syncthreads();
    #pragma unroll
    for (int i = 0; i < 2; i++) {
        int ck = tid + 256 * i;
        int c = ck >> 3, ch = ck & 7;
        u16x8 val = *reinterpret_cast<const u16x8*>(&St[c * 64 + ((ch ^ ((c >> 4) & 3)) << 3)]);
        *reinterpret_cast<u16x8*>(dst + (size_t)(c0 + c) * R + r0 + ch * 8) = val;
    }
}

// ---------------------------------------------------------------------------
// V-part of qkv [b,t,4096+h*128+d] (bf16) -> VT [b][h][d][t'] (bf16), where
// within each 32-t block, t' is PERMUTED so flash's PV contraction-index
// order matches the swapped-QK^T P layout:
//   chunk ch (8 elems) = {32*(ch>>2) + 4*(ch&3) + 0..3,
//                         32*(ch>>2) + 16 + 4*(ch&3) + 0..3}
// (a permutation of the contraction axis applied to both P and V — legal.)
// ---------------------------------------------------------------------------
__global__ __launch_bounds__(256) void vtrans(
    const unsigned short* __restrict__ qkv, unsigned short* __restrict__ VT)
{
    const int T = 2048, CH = 6144;
    __shared__ unsigned short St[64 * 64];
    const int tid = threadIdx.x;
    const int bh = blockIdx.z;
    const int b = bh >> 4, h = bh & 15;
    const int t0 = blockIdx.x * 64, d0 = blockIdx.y * 64;
    const int lr  = tid >> 2;
    const int lcb = (tid & 3) * 16;
    const unsigned short* sp = qkv + (size_t)(b * T + t0 + lr) * CH + 4096 + h * 128 + d0 + lcb;
    u16x8 v0 = *reinterpret_cast<const u16x8*>(sp);
    u16x8 v1 = *reinterpret_cast<const u16x8*>(sp + 8);
    #pragma unroll
    for (int e = 0; e < 8; e++) {
        int c = lcb + e;
        St[c * 64 + (((lr >> 3) ^ ((c >> 4) & 3)) << 3) + (lr & 7)] = v0[e];
        c = lcb + 8 + e;
        St[c * 64 + (((lr >> 3) ^ ((c >> 4) & 3)) << 3) + (lr & 7)] = v1[e];
    }
    __syncthreads();
    #pragma unroll
    for (int i = 0; i < 2; i++) {
        int ck = tid + 256 * i;
        int d = ck >> 3, ch = ck & 7;
        const int Q = ch & 3, B32 = ch >> 2;
        u16x8 val;
        #pragma unroll
        for (int e = 0; e < 4; e++) {
            int ta = 32 * B32 + 4 * Q + e;        // first half of chunk
            int tb = ta + 16;                     // second half
            val[e]     = St[d * 64 + (((ta >> 3) ^ ((d >> 4) & 3)) << 3) + (ta & 7)];
            val[4 + e] = St[d * 64 + (((tb >> 3) ^ ((d >> 4) & 3)) << 3) + (tb & 7)];
        }
        *reinterpret_cast<u16x8*>(VT + (size_t)(bh * 128 + d0 + d) * T + t0 + ch * 8) = val;
    }
}

// ---------------------------------------------------------------------------
// m97-style GEMM: C[M,N] = A[M,K] @ BT[N,K]^T, bf16 in, fp32 acc.
// ---------------------------------------------------------------------------
__global__ __launch_bounds__(256) void gemm_bt(
    const unsigned short* __restrict__ A,   // [M][K] bf16
    const unsigned short* __restrict__ BT,  // [N][K] bf16
    void* __restrict__ C, int M, int N, int K, int cF32)
{
    __shared__ unsigned short As[128 * 32];
    __shared__ unsigned short Bs[128 * 32];
    const int tid = threadIdx.x;
    const int w = tid >> 6, lane = tid & 63;
    const int quad = lane >> 4, l16 = lane & 15;
    const int wm = (w >> 1) * 64, wn = (w & 1) * 64;
    const int m0 = blockIdx.y * 128, n0 = blockIdx.x * 128;

    const int srow = w * 16 + (lane >> 2);
    const int scol = (lane & 3) * 8;
    const unsigned short* aG = A  + (size_t)(m0 + srow) * K + scol;
    const unsigned short* bG = BT + (size_t)(n0 + srow) * K + scol;
    unsigned short* aL = As + (w * 16) * 32;
    unsigned short* bL = Bs + (w * 16) * 32;

    f32x4 acc[4][4] = {};

    for (int k0 = 0; k0 < K; k0 += 32) {
        async16(aG + k0, aL);
        async16(aG + (size_t)64 * K + k0, aL + 64 * 32);
        async16(bG + k0, bL);
        async16(bG + (size_t)64 * K + k0, bL + 64 * 32);
        __syncthreads();

        bf16x8 af[4], bf[4];
        #pragma unroll
        for (int i = 0; i < 4; i++)
            af[i] = *reinterpret_cast<const bf16x8*>(&As[(wm + i * 16 + l16) * 32 + quad * 8]);
        #pragma unroll
        for (int c = 0; c < 4; c++)
            bf[c] = *reinterpret_cast<const bf16x8*>(&Bs[(wn + c * 16 + l16) * 32 + quad * 8]);
        #pragma unroll
        for (int i = 0; i < 4; i++)
            #pragma unroll
            for (int c = 0; c < 4; c++)
                acc[i][c] = __builtin_amdgcn_mfma_f32_16x16x32_bf16(af[i], bf[c], acc[i][c], 0, 0, 0);
        __syncthreads();
    }

    #pragma unroll
    for (int i = 0; i < 4; i++)
        #pragma unroll
        for (int c = 0; c < 4; c++)
            #pragma unroll
            for (int r = 0; r < 4; r++) {
                const int row = m0 + wm + i * 16 + quad * 4 + r;
                const int col = n0 + wn + c * 16 + l16;
                const size_t off = (size_t)row * N + col;
                if (cF32) ((float*)C)[off] = acc[i][c][r];
                else ((unsigned short*)C)[off] = f2bf(acc[i][c][r]);
            }
}

// ---------------------------------------------------------------------------
// Flash attention v2 (causal), swapped-QK^T / lane-local softmax, and now
// DOUBLE-BUFFERED K/V staging with a counted-vmcnt 2-phase pipeline:
//   prologue: stage(tile0) ; vmcnt(0) ; barrier
//   loop t  : stage(tile t+1 -> other buf) ; compute(tile t) ;
//             lgkmcnt(0) vmcnt(0) ; s_barrier ; swap
// The prefetch is in flight across the ENTIRE compute of tile t (QK^T +
// softmax + PV), hiding L2/HBM latency; one barrier per tile instead of two.
// Raw s_barrier via asm with "memory" clobber (no compiler vmcnt(0) drain
// at the top of compute). s_setprio(1) wraps the MFMA clusters (T5).
// ---------------------------------------------------------------------------
__global__ __launch_bounds__(256, 2) void flash_attn(
    const unsigned short* __restrict__ qkv,
    const unsigned short* __restrict__ VT,
    unsigned short* __restrict__ Out)
{
    const int T = 2048, CH = 6144;
    __shared__ unsigned short KsBuf[2][64 * 128];   // [kv][d-chunk swizzled]
    __shared__ unsigned short VtBuf[2][128 * 64];   // [d][kv'-chunk swizzled]

    const int tid = threadIdx.x;
    const int w = tid >> 6, lane = tid & 63;
    const int quad = lane >> 4, l16 = lane & 15;
    const int bh = blockIdx.y, b = bh >> 4, h = bh & 15;
    const int q0 = (gridDim.x - 1 - blockIdx.x) * 128;   // heavy blocks first

    const float sc = 0.08838834764831845f * 1.4426950408889634f;
    const float NINF = -__builtin_inff();

    // Q fragments (B-operand), scale folded in
    bf16x8 qf[2][4];
    #pragma unroll
    for (int st = 0; st < 2; st++) {
        const unsigned short* qrow = qkv + (size_t)(b * T + q0 + w * 32 + st * 16 + l16) * CH + h * 128;
        #pragma unroll
        for (int dc = 0; dc < 4; dc++) {
            u16x8 raw = *reinterpret_cast<const u16x8*>(qrow + dc * 32 + quad * 8);
            u16x8 scl;
            #pragma unroll
            for (int e = 0; e < 8; e++) {
                float f = __builtin_bit_cast(float, (unsigned int)raw[e] << 16);
                scl[e] = f2bf(f * sc);
            }
            qf[st][dc] = __builtin_bit_cast(bf16x8, scl);
        }
    }

    f32x4 o[2][8] = {};
    float m_i[2] = {NINF, NINF};
    float l_i[2] = {0.f, 0.f};
    const int xsw = l16 & 7;

    // staging: 8 global_load_lds per lane into (kp, vp) for kv tile at kv0
    const int kRow = (lane >> 4);              // within 16-row group
    const int kCh  = lane & 15;
    const int vRow = (lane >> 3);              // within 32-row group
    const int vCh  = lane & 7;

    auto stageKV = [&](int kv0, unsigned short* kp, unsigned short* vp) {
        #pragma unroll
        for (int i = 0; i < 4; i++) {
            const int r0 = i * 16 + w * 4;
            const int kv = r0 + kRow;
            const int ch = kCh ^ (kv & 7);
            async16(qkv + (size_t)(b * T + kv0 + kv) * CH + 2048 + h * 128 + ch * 8,
                    kp + r0 * 128);
        }
        #pragma unroll
        for (int i = 0; i < 4; i++) {
            const int r0 = i * 32 + w * 8;
            const int d = r0 + vRow;
            const int ch = vCh ^ (d & 7);
            async16(VT + ((size_t)bh * 128 + d) * T + kv0 + ch * 8,
                    vp + r0 * 64);
        }
    };

    unsigned short* kc = KsBuf[0];
    unsigned short* vc = VtBuf[0];
    unsigned short* kn = KsBuf[1];
    unsigned short* vn = VtBuf[1];

    const int nt = (q0 + 128) / 64;

    stageKV(0, kc, vc);
    asm volatile("s_waitcnt vmcnt(0)\n\ts_barrier" ::: "memory");

    for (int t = 0; t < nt; ++t) {
        const int kv0 = t * 64;
        if (t + 1 < nt) stageKV((t + 1) * 64, kn, vn);

        // ---- S^T = K Q^T : s[st][nt][r] = S[q=qs+l16][kv0 + ntt*16 + quad*4 + r] ----
        f32x4 s[2][4] = {};
        __builtin_amdgcn_s_setprio(1);
        #pragma unroll
        for (int dc = 0; dc < 4; dc++)
            #pragma unroll
            for (int ntt = 0; ntt < 4; ntt++) {
                bf16x8 kf = *reinterpret_cast<const bf16x8*>(
                    &kc[(ntt * 16 + l16) * 128 + (((dc * 4 + quad) ^ xsw) << 3)]);
                s[0][ntt] = __builtin_amdgcn_mfma_f32_16x16x32_bf16(kf, qf[0][dc], s[0][ntt], 0, 0, 0);
                s[1][ntt] = __builtin_amdgcn_mfma_f32_16x16x32_bf16(kf, qf[1][dc], s[1][ntt], 0, 0, 0);
            }
        __builtin_amdgcn_s_setprio(0);

        // ---- softmax, lane-local rows ----
        unsigned int pk[2][4][2];
        #pragma unroll
        for (int st = 0; st < 2; st++) {
            const int qs = q0 + w * 32 + st * 16;
            const int qrow = qs + l16;
            if (kv0 + 63 > qs) {                     // diagonal: apply causal mask
                #pragma unroll
                for (int ntt = 0; ntt < 4; ntt++)
                    #pragma unroll
                    for (int r = 0; r < 4; r++)
                        if (kv0 + ntt * 16 + quad * 4 + r > qrow) s[st][ntt][r] = NINF;
            }
            float mx = fmaxf(fmaxf(fmaxf(s[st][0][0], s[st][0][1]), fmaxf(s[st][0][2], s[st][0][3])),
                             fmaxf(fmaxf(s[st][1][0], s[st][1][1]), fmaxf(s[st][1][2], s[st][1][3])));
            mx = fmaxf(mx,
                 fmaxf(fmaxf(fmaxf(s[st][2][0], s[st][2][1]), fmaxf(s[st][2][2], s[st][2][3])),
                       fmaxf(fmaxf(s[st][3][0], s[st][3][1]), fmaxf(s[st][3][2], s[st][3][3]))));
            mx = fmaxf(mx, __shfl_xor(mx, 16));
            mx = fmaxf(mx, __shfl_xor(mx, 32));

            const float mold = m_i[st];
            if (!__all(mx <= mold + 8.0f)) {         // rescale (rare after tile 0)
                const float mnew = fmaxf(mold, mx);
                const float alpha = exp2f(mold - mnew);
                m_i[st] = mnew;
                l_i[st] *= alpha;
                #pragma unroll
                for (int r = 0; r < 4; r++) {
                    const float a = __shfl(alpha, quad * 4 + r);
                    #pragma unroll
                    for (int c = 0; c < 8; c++) o[st][c][r] *= a;
                }
            }
            const float m = m_i[st];
            float p[4][4];
            #pragma unroll
            for (int ntt = 0; ntt < 4; ntt++)
                #pragma unroll
                for (int r = 0; r < 4; r++)
                    p[ntt][r] = exp2f(s[st][ntt][r] - m);
            float ps = ((p[0][0] + p[0][1]) + (p[0][2] + p[0][3]))
                     + ((p[1][0] + p[1][1]) + (p[1][2] + p[1][3]))
                     + ((p[2][0] + p[2][1]) + (p[2][2] + p[2][3]))
                     + ((p[3][0] + p[3][1]) + (p[3][2] + p[3][3]));
            ps += __shfl_xor(ps, 16);
            ps += __shfl_xor(ps, 32);
            l_i[st] += ps;
            #pragma unroll
            for (int ntt = 0; ntt < 4; ntt++) {
                pk[st][ntt][0] = cvt_pk_bf16(p[ntt][0], p[ntt][1]);
                pk[st][ntt][1] = cvt_pk_bf16(p[ntt][2], p[ntt][3]);
            }
        }

        // ---- O += P V : pf comes straight from pk (permuted-k, no exchange) ----
        __builtin_amdgcn_s_setprio(1);
        #pragma unroll
        for (int kc2 = 0; kc2 < 2; kc2++) {
            u32x4 a0, a1;
            a0[0] = pk[0][2*kc2][0];   a0[1] = pk[0][2*kc2][1];
            a0[2] = pk[0][2*kc2+1][0]; a0[3] = pk[0][2*kc2+1][1];
            a1[0] = pk[1][2*kc2][0];   a1[1] = pk[1][2*kc2][1];
            a1[2] = pk[1][2*kc2+1][0]; a1[3] = pk[1][2*kc2+1][1];
            const bf16x8 pf0 = __builtin_bit_cast(bf16x8, a0);
            const bf16x8 pf1 = __builtin_bit_cast(bf16x8, a1);
            #pragma unroll
            for (int c = 0; c < 8; c++) {
                bf16x8 vf = *reinterpret_cast<const bf16x8*>(
                    &vc[(c * 16 + l16) * 64 + (((kc2 * 4 + quad) ^ xsw) << 3)]);
                o[0][c] = __builtin_amdgcn_mfma_f32_16x16x32_bf16(pf0, vf, o[0][c], 0, 0, 0);
                o[1][c] = __builtin_amdgcn_mfma_f32_16x16x32_bf16(pf1, vf, o[1][c], 0, 0, 0);
            }
        }
        __builtin_amdgcn_s_setprio(0);

        // all ds_reads of this tile retired; prefetch landed; then cross
        asm volatile("s_waitcnt vmcnt(0) lgkmcnt(0)\n\ts_barrier" ::: "memory");

        unsigned short* tp;
        tp = kc; kc = kn; kn = tp;
        tp = vc; vc = vn; vn = tp;
    }

    #pragma unroll
    for (int st = 0; st < 2; st++)
        #pragma unroll
        for (int r = 0; r < 4; r++) {
            const float linv = 1.0f / __shfl(l_i[st], quad * 4 + r);
            const int row = q0 + w * 32 + st * 16 + quad * 4 + r;
            const size_t base = (size_t)(b * T + row) * 2048 + h * 128;
            #pragma unroll
            for (int c = 0; c < 8; c++)
                Out[base + c * 16 + l16] = f2bf(o[st][c][r] * linv);
        }
}

extern "C" void kernel_launch(void* const* d_in, const int* in_sizes, int n_in,
                              void* d_out, int out_size, void* d_ws, size_t ws_size,
                              hipStream_t stream) {
    const int B = 2, T = 2048, C = 2048;
    const float* x    = (const float*)d_in[0];
    const float* Wqkv = (const float*)d_in[2];   // [C][3C] fp32
    const float* Wout = (const float*)d_in[3];   // [C][C]  fp32
    const int M = B * T;                         // 4096

    char* ws = (char*)d_ws;
    unsigned short* qkv   = (unsigned short*)ws;                       // +0
    unsigned short* xb    = (unsigned short*)(ws + 50331648);          // region A
    unsigned short* WoutT = xb;
    unsigned short* WqkvT = (unsigned short*)(ws + 67108864);          // region B
    unsigned short* VTp   = WqkvT;
    unsigned short* O     = (unsigned short*)(ws + 92274688);

    // 1) casts for GEMM1
    cast_bf16<<<dim3(M * C / 8 / 256), 256, 0, stream>>>(x, xb, M * C / 8);
    transpose_cast_f32<<<dim3(3 * C / 64, C / 64), 256, 0, stream>>>(Wqkv, WqkvT, C, 3 * C);
    // 2) qkv = xb @ WqkvT^T
    gemm_bt<<<dim3(3 * C / 128, M / 128), 256, 0, stream>>>(xb, WqkvT, qkv, M, 3 * C, C, 0);
    // 3) V transpose (k-permuted layout) and Wout cast
    vtrans<<<dim3(T / 64, 2, B * 16), 256, 0, stream>>>(qkv, VTp);
    transpose_cast_f32<<<dim3(C / 64, C / 64), 256, 0, stream>>>(Wout, WoutT, C, C);
    // 4) flash attention
    flash_attn<<<dim3(T / 128, B * 16), 256, 0, stream>>>(qkv, VTp, O);
    // 5) out = O @ WoutT^T (fp32 out)
    gemm_bt<<<dim3(C / 128, M / 128), 256, 0, stream>>>(O, WoutT, d_out, M, C, C, 1);
}

// Round 4
// 421.635 us; speedup vs baseline: 1.2577x; 1.0714x over previous
//
#include <hip/hip_runtime.h>
#include <stdint.h>

typedef __bf16 bf16x8 __attribute__((ext_vector_type(8)));
typedef float f32x4 __attribute__((ext_vector_type(4)));
typedef unsigned short u16x8 __attribute__((ext_vector_type(8)));
typedef unsigned int u32x4 __attribute__((ext_vector_type(4)));

__device__ __forceinline__ unsigned short f2bf(float f) {
    unsigned int u = __builtin_bit_cast(unsigned int, f);
    unsigned int r = u + 0x7fffu + ((u >> 16) & 1u);
    return (unsigned short)(r >> 16);
}

// v_cvt_pk_bf16_f32: lo <- bf16(a), hi <- bf16(b)
__device__ __forceinline__ unsigned int cvt_pk_bf16(float a, float b) {
    unsigned int r;
    asm("v_cvt_pk_bf16_f32 %0, %1, %2" : "=v"(r) : "v"(a), "v"(b));
    return r;
}

// async global->LDS, 16B per lane. LDS dest = wave-uniform base + lane*16.
__device__ __forceinline__ void async16(const void* g, void* l) {
    __builtin_amdgcn_global_load_lds(
        (const __attribute__((address_space(1))) void*)g,
        (__attribute__((address_space(3))) void*)l, 16, 0, 0);
}

// ---------------------------------------------------------------------------
// x fp32 -> bf16, elementwise (8 elems/thread)
// ---------------------------------------------------------------------------
__global__ __launch_bounds__(256) void cast_bf16(
    const float* __restrict__ src, unsigned short* __restrict__ dst, int n8)
{
    int i = blockIdx.x * 256 + threadIdx.x;
    if (i >= n8) return;
    const float* f = src + (size_t)i * 8;
    f32x4 a = *reinterpret_cast<const f32x4*>(f);
    f32x4 b = *reinterpret_cast<const f32x4*>(f + 4);
    u16x8 r;
    r[0]=f2bf(a[0]); r[1]=f2bf(a[1]); r[2]=f2bf(a[2]); r[3]=f2bf(a[3]);
    r[4]=f2bf(b[0]); r[5]=f2bf(b[1]); r[6]=f2bf(b[2]); r[7]=f2bf(b[3]);
    *reinterpret_cast<u16x8*>(dst + (size_t)i * 8) = r;
}

// ---------------------------------------------------------------------------
// W fp32 [R][Cc] -> bf16 W^T [Cc][R]. 64x64 tiles, XOR-swizzled LDS
// ---------------------------------------------------------------------------
__global__ __launch_bounds__(256) void transpose_cast_f32(
    const float* __restrict__ src, unsigned short* __restrict__ dst, int R, int Cc)
{
    __shared__ unsigned short St[64 * 64];
    const int tid = threadIdx.x;
    const int r0 = blockIdx.y * 64, c0 = blockIdx.x * 64;
    const int lr  = tid >> 2;          // 0..63
    const int lcb = (tid & 3) * 16;    // 0,16,32,48
    const float* sp = src + (size_t)(r0 + lr) * Cc + c0 + lcb;
    #pragma unroll
    for (int u = 0; u < 4; u++) {
        f32x4 v = *reinterpret_cast<const f32x4*>(sp + 4 * u);
        #pragma unroll
        for (int e = 0; e < 4; e++) {
            int c = lcb + 4 * u + e;
            St[c * 64 + (((lr >> 3) ^ ((c >> 4) & 3)) << 3) + (lr & 7)] = f2bf(v[e]);
        }
    }
    __syncthreads();
    #pragma unroll
    for (int i = 0; i < 2; i++) {
        int ck = tid + 256 * i;
        int c = ck >> 3, ch = ck & 7;
        u16x8 val = *reinterpret_cast<const u16x8*>(&St[c * 64 + ((ch ^ ((c >> 4) & 3)) << 3)]);
        *reinterpret_cast<u16x8*>(dst + (size_t)(c0 + c) * R + r0 + ch * 8) = val;
    }
}

// ---------------------------------------------------------------------------
// V-part of qkv -> VT [b][h][d][t'] with per-32 t-permutation matching the
// swapped-QK^T P layout (see flash_attn).
// ---------------------------------------------------------------------------
__global__ __launch_bounds__(256) void vtrans(
    const unsigned short* __restrict__ qkv, unsigned short* __restrict__ VT)
{
    const int T = 2048, CH = 6144;
    __shared__ unsigned short St[64 * 64];
    const int tid = threadIdx.x;
    const int bh = blockIdx.z;
    const int b = bh >> 4, h = bh & 15;
    const int t0 = blockIdx.x * 64, d0 = blockIdx.y * 64;
    const int lr  = tid >> 2;
    const int lcb = (tid & 3) * 16;
    const unsigned short* sp = qkv + (size_t)(b * T + t0 + lr) * CH + 4096 + h * 128 + d0 + lcb;
    u16x8 v0 = *reinterpret_cast<const u16x8*>(sp);
    u16x8 v1 = *reinterpret_cast<const u16x8*>(sp + 8);
    #pragma unroll
    for (int e = 0; e < 8; e++) {
        int c = lcb + e;
        St[c * 64 + (((lr >> 3) ^ ((c >> 4) & 3)) << 3) + (lr & 7)] = v0[e];
        c = lcb + 8 + e;
        St[c * 64 + (((lr >> 3) ^ ((c >> 4) & 3)) << 3) + (lr & 7)] = v1[e];
    }
    __syncthreads();
    #pragma unroll
    for (int i = 0; i < 2; i++) {
        int ck = tid + 256 * i;
        int d = ck >> 3, ch = ck & 7;
        const int Q = ch & 3, B32 = ch >> 2;
        u16x8 val;
        #pragma unroll
        for (int e = 0; e < 4; e++) {
            int ta = 32 * B32 + 4 * Q + e;        // first half of chunk
            int tb = ta + 16;                     // second half
            val[e]     = St[d * 64 + (((ta >> 3) ^ ((d >> 4) & 3)) << 3) + (ta & 7)];
            val[4 + e] = St[d * 64 + (((tb >> 3) ^ ((d >> 4) & 3)) << 3) + (tb & 7)];
        }
        *reinterpret_cast<u16x8*>(VT + (size_t)(bh * 128 + d0 + d) * T + t0 + ch * 8) = val;
    }
}

// ---------------------------------------------------------------------------
// m97-style GEMM, now DOUBLE-BUFFERED with the counted-vmcnt single-barrier
// pipeline proven by flash_attn (round 2):
//   prologue: stage(tile0 -> buf0) ; vmcnt(0) ; s_barrier
//   loop t  : stage(tile t+1 -> buf[ct^1]) ; frags from buf[ct] ; 16 MFMA ;
//             s_waitcnt vmcnt(0) lgkmcnt(0) ; s_barrier ; ct ^= 1
// One barrier per K-tile (was 2); the prefetch for t+1 is in flight across
// the whole compute of tile t, so the vmcnt(0) at tile end waits on a load
// that has had the full tile's compute to land instead of stalling cold.
// lgkmcnt(0) before the barrier guarantees all ds_reads of buf[ct] retired
// before any wave can overwrite it next iteration (WAR safety).
// Tile 128x128, 4 waves, LDS 2x16KB = 32KB.
// ---------------------------------------------------------------------------
__global__ __launch_bounds__(256) void gemm_bt(
    const unsigned short* __restrict__ A,   // [M][K] bf16
    const unsigned short* __restrict__ BT,  // [N][K] bf16
    void* __restrict__ C, int M, int N, int K, int cF32)
{
    __shared__ unsigned short As[2][128 * 32];
    __shared__ unsigned short Bs[2][128 * 32];
    const int tid = threadIdx.x;
    const int w = tid >> 6, lane = tid & 63;
    const int quad = lane >> 4, l16 = lane & 15;
    const int wm = (w >> 1) * 64, wn = (w & 1) * 64;
    const int m0 = blockIdx.y * 128, n0 = blockIdx.x * 128;

    const int srow = w * 16 + (lane >> 2);
    const int scol = (lane & 3) * 8;
    const unsigned short* aG = A  + (size_t)(m0 + srow) * K + scol;
    const unsigned short* bG = BT + (size_t)(n0 + srow) * K + scol;
    const int ldsO = (w * 16) * 32;            // wave-uniform LDS offset

    f32x4 acc[4][4] = {};
    const int nkt = K >> 5;

    // prologue: stage tile 0
    async16(aG, &As[0][ldsO]);
    async16(aG + (size_t)64 * K, &As[0][ldsO + 64 * 32]);
    async16(bG, &Bs[0][ldsO]);
    async16(bG + (size_t)64 * K, &Bs[0][ldsO + 64 * 32]);
    asm volatile("s_waitcnt vmcnt(0)\n\ts_barrier" ::: "memory");

    int ct = 0;
    for (int t = 0; t < nkt; ++t) {
        // stage next tile into the other buffer (in flight across compute)
        if (t + 1 < nkt) {
            const int k1 = (t + 1) * 32;
            async16(aG + k1, &As[ct ^ 1][ldsO]);
            async16(aG + (size_t)64 * K + k1, &As[ct ^ 1][ldsO + 64 * 32]);
            async16(bG + k1, &Bs[ct ^ 1][ldsO]);
            async16(bG + (size_t)64 * K + k1, &Bs[ct ^ 1][ldsO + 64 * 32]);
        }

        bf16x8 af[4], bf[4];
        #pragma unroll
        for (int i = 0; i < 4; i++)
            af[i] = *reinterpret_cast<const bf16x8*>(&As[ct][(wm + i * 16 + l16) * 32 + quad * 8]);
        #pragma unroll
        for (int c = 0; c < 4; c++)
            bf[c] = *reinterpret_cast<const bf16x8*>(&Bs[ct][(wn + c * 16 + l16) * 32 + quad * 8]);

        __builtin_amdgcn_s_setprio(1);
        #pragma unroll
        for (int i = 0; i < 4; i++)
            #pragma unroll
            for (int c = 0; c < 4; c++)
                acc[i][c] = __builtin_amdgcn_mfma_f32_16x16x32_bf16(af[i], bf[c], acc[i][c], 0, 0, 0);
        __builtin_amdgcn_s_setprio(0);

        // ds_reads retired (WAR) + prefetch landed; then cross together
        asm volatile("s_waitcnt vmcnt(0) lgkmcnt(0)\n\ts_barrier" ::: "memory");
        ct ^= 1;
    }

    #pragma unroll
    for (int i = 0; i < 4; i++)
        #pragma unroll
        for (int c = 0; c < 4; c++)
            #pragma unroll
            for (int r = 0; r < 4; r++) {
                const int row = m0 + wm + i * 16 + quad * 4 + r;
                const int col = n0 + wn + c * 16 + l16;
                const size_t off = (size_t)row * N + col;
                if (cF32) ((float*)C)[off] = acc[i][c][r];
                else ((unsigned short*)C)[off] = f2bf(acc[i][c][r]);
            }
}

// ---------------------------------------------------------------------------
// Flash attention v2 (causal), swapped-QK^T / lane-local softmax,
// double-buffered K/V staging with counted-vmcnt pipeline (round-2 version,
// unchanged — it measured well).
// ---------------------------------------------------------------------------
__global__ __launch_bounds__(256, 2) void flash_attn(
    const unsigned short* __restrict__ qkv,
    const unsigned short* __restrict__ VT,
    unsigned short* __restrict__ Out)
{
    const int T = 2048, CH = 6144;
    __shared__ unsigned short KsBuf[2][64 * 128];   // [kv][d-chunk swizzled]
    __shared__ unsigned short VtBuf[2][128 * 64];   // [d][kv'-chunk swizzled]

    const int tid = threadIdx.x;
    const int w = tid >> 6, lane = tid & 63;
    const int quad = lane >> 4, l16 = lane & 15;
    const int bh = blockIdx.y, b = bh >> 4, h = bh & 15;
    const int q0 = (gridDim.x - 1 - blockIdx.x) * 128;   // heavy blocks first

    const float sc = 0.08838834764831845f * 1.4426950408889634f;
    const float NINF = -__builtin_inff();

    // Q fragments (B-operand), scale folded in
    bf16x8 qf[2][4];
    #pragma unroll
    for (int st = 0; st < 2; st++) {
        const unsigned short* qrow = qkv + (size_t)(b * T + q0 + w * 32 + st * 16 + l16) * CH + h * 128;
        #pragma unroll
        for (int dc = 0; dc < 4; dc++) {
            u16x8 raw = *reinterpret_cast<const u16x8*>(qrow + dc * 32 + quad * 8);
            u16x8 scl;
            #pragma unroll
            for (int e = 0; e < 8; e++) {
                float f = __builtin_bit_cast(float, (unsigned int)raw[e] << 16);
                scl[e] = f2bf(f * sc);
            }
            qf[st][dc] = __builtin_bit_cast(bf16x8, scl);
        }
    }

    f32x4 o[2][8] = {};
    float m_i[2] = {NINF, NINF};
    float l_i[2] = {0.f, 0.f};
    const int xsw = l16 & 7;

    const int kRow = (lane >> 4);
    const int kCh  = lane & 15;
    const int vRow = (lane >> 3);
    const int vCh  = lane & 7;

    auto stageKV = [&](int kv0, unsigned short* kp, unsigned short* vp) {
        #pragma unroll
        for (int i = 0; i < 4; i++) {
            const int r0 = i * 16 + w * 4;
            const int kv = r0 + kRow;
            const int ch = kCh ^ (kv & 7);
            async16(qkv + (size_t)(b * T + kv0 + kv) * CH + 2048 + h * 128 + ch * 8,
                    kp + r0 * 128);
        }
        #pragma unroll
        for (int i = 0; i < 4; i++) {
            const int r0 = i * 32 + w * 8;
            const int d = r0 + vRow;
            const int ch = vCh ^ (d & 7);
            async16(VT + ((size_t)bh * 128 + d) * T + kv0 + ch * 8,
                    vp + r0 * 64);
        }
    };

    unsigned short* kc = KsBuf[0];
    unsigned short* vc = VtBuf[0];
    unsigned short* kn = KsBuf[1];
    unsigned short* vn = VtBuf[1];

    const int nt = (q0 + 128) / 64;

    stageKV(0, kc, vc);
    asm volatile("s_waitcnt vmcnt(0)\n\ts_barrier" ::: "memory");

    for (int t = 0; t < nt; ++t) {
        const int kv0 = t * 64;
        if (t + 1 < nt) stageKV((t + 1) * 64, kn, vn);

        // ---- S^T = K Q^T ----
        f32x4 s[2][4] = {};
        __builtin_amdgcn_s_setprio(1);
        #pragma unroll
        for (int dc = 0; dc < 4; dc++)
            #pragma unroll
            for (int ntt = 0; ntt < 4; ntt++) {
                bf16x8 kf = *reinterpret_cast<const bf16x8*>(
                    &kc[(ntt * 16 + l16) * 128 + (((dc * 4 + quad) ^ xsw) << 3)]);
                s[0][ntt] = __builtin_amdgcn_mfma_f32_16x16x32_bf16(kf, qf[0][dc], s[0][ntt], 0, 0, 0);
                s[1][ntt] = __builtin_amdgcn_mfma_f32_16x16x32_bf16(kf, qf[1][dc], s[1][ntt], 0, 0, 0);
            }
        __builtin_amdgcn_s_setprio(0);

        // ---- softmax, lane-local rows ----
        unsigned int pk[2][4][2];
        #pragma unroll
        for (int st = 0; st < 2; st++) {
            const int qs = q0 + w * 32 + st * 16;
            const int qrow = qs + l16;
            if (kv0 + 63 > qs) {                     // diagonal: causal mask
                #pragma unroll
                for (int ntt = 0; ntt < 4; ntt++)
                    #pragma unroll
                    for (int r = 0; r < 4; r++)
                        if (kv0 + ntt * 16 + quad * 4 + r > qrow) s[st][ntt][r] = NINF;
            }
            float mx = fmaxf(fmaxf(fmaxf(s[st][0][0], s[st][0][1]), fmaxf(s[st][0][2], s[st][0][3])),
                             fmaxf(fmaxf(s[st][1][0], s[st][1][1]), fmaxf(s[st][1][2], s[st][1][3])));
            mx = fmaxf(mx,
                 fmaxf(fmaxf(fmaxf(s[st][2][0], s[st][2][1]), fmaxf(s[st][2][2], s[st][2][3])),
                       fmaxf(fmaxf(s[st][3][0], s[st][3][1]), fmaxf(s[st][3][2], s[st][3][3]))));
            mx = fmaxf(mx, __shfl_xor(mx, 16));
            mx = fmaxf(mx, __shfl_xor(mx, 32));

            const float mold = m_i[st];
            if (!__all(mx <= mold + 8.0f)) {         // rescale (rare)
                const float mnew = fmaxf(mold, mx);
                const float alpha = exp2f(mold - mnew);
                m_i[st] = mnew;
                l_i[st] *= alpha;
                #pragma unroll
                for (int r = 0; r < 4; r++) {
                    const float a = __shfl(alpha, quad * 4 + r);
                    #pragma unroll
                    for (int c = 0; c < 8; c++) o[st][c][r] *= a;
                }
            }
            const float m = m_i[st];
            float p[4][4];
            #pragma unroll
            for (int ntt = 0; ntt < 4; ntt++)
                #pragma unroll
                for (int r = 0; r < 4; r++)
                    p[ntt][r] = exp2f(s[st][ntt][r] - m);
            float ps = ((p[0][0] + p[0][1]) + (p[0][2] + p[0][3]))
                     + ((p[1][0] + p[1][1]) + (p[1][2] + p[1][3]))
                     + ((p[2][0] + p[2][1]) + (p[2][2] + p[2][3]))
                     + ((p[3][0] + p[3][1]) + (p[3][2] + p[3][3]));
            ps += __shfl_xor(ps, 16);
            ps += __shfl_xor(ps, 32);
            l_i[st] += ps;
            #pragma unroll
            for (int ntt = 0; ntt < 4; ntt++) {
                pk[st][ntt][0] = cvt_pk_bf16(p[ntt][0], p[ntt][1]);
                pk[st][ntt][1] = cvt_pk_bf16(p[ntt][2], p[ntt][3]);
            }
        }

        // ---- O += P V ----
        __builtin_amdgcn_s_setprio(1);
        #pragma unroll
        for (int kc2 = 0; kc2 < 2; kc2++) {
            u32x4 a0, a1;
            a0[0] = pk[0][2*kc2][0];   a0[1] = pk[0][2*kc2][1];
            a0[2] = pk[0][2*kc2+1][0]; a0[3] = pk[0][2*kc2+1][1];
            a1[0] = pk[1][2*kc2][0];   a1[1] = pk[1][2*kc2][1];
            a1[2] = pk[1][2*kc2+1][0]; a1[3] = pk[1][2*kc2+1][1];
            const bf16x8 pf0 = __builtin_bit_cast(bf16x8, a0);
            const bf16x8 pf1 = __builtin_bit_cast(bf16x8, a1);
            #pragma unroll
            for (int c = 0; c < 8; c++) {
                bf16x8 vf = *reinterpret_cast<const bf16x8*>(
                    &vc[(c * 16 + l16) * 64 + (((kc2 * 4 + quad) ^ xsw) << 3)]);
                o[0][c] = __builtin_amdgcn_mfma_f32_16x16x32_bf16(pf0, vf, o[0][c], 0, 0, 0);
                o[1][c] = __builtin_amdgcn_mfma_f32_16x16x32_bf16(pf1, vf, o[1][c], 0, 0, 0);
            }
        }
        __builtin_amdgcn_s_setprio(0);

        asm volatile("s_waitcnt vmcnt(0) lgkmcnt(0)\n\ts_barrier" ::: "memory");

        unsigned short* tp;
        tp = kc; kc = kn; kn = tp;
        tp = vc; vc = vn; vn = tp;
    }

    #pragma unroll
    for (int st = 0; st < 2; st++)
        #pragma unroll
        for (int r = 0; r < 4; r++) {
            const float linv = 1.0f / __shfl(l_i[st], quad * 4 + r);
            const int row = q0 + w * 32 + st * 16 + quad * 4 + r;
            const size_t base = (size_t)(b * T + row) * 2048 + h * 128;
            #pragma unroll
            for (int c = 0; c < 8; c++)
                Out[base + c * 16 + l16] = f2bf(o[st][c][r] * linv);
        }
}

extern "C" void kernel_launch(void* const* d_in, const int* in_sizes, int n_in,
                              void* d_out, int out_size, void* d_ws, size_t ws_size,
                              hipStream_t stream) {
    const int B = 2, T = 2048, C = 2048;
    const float* x    = (const float*)d_in[0];
    const float* Wqkv = (const float*)d_in[2];   // [C][3C] fp32
    const float* Wout = (const float*)d_in[3];   // [C][C]  fp32
    const int M = B * T;                         // 4096

    char* ws = (char*)d_ws;
    unsigned short* qkv   = (unsigned short*)ws;                       // +0
    unsigned short* xb    = (unsigned short*)(ws + 50331648);          // region A
    unsigned short* WoutT = xb;
    unsigned short* WqkvT = (unsigned short*)(ws + 67108864);          // region B
    unsigned short* VTp   = WqkvT;
    unsigned short* O     = (unsigned short*)(ws + 92274688);

    // 1) casts for GEMM1
    cast_bf16<<<dim3(M * C / 8 / 256), 256, 0, stream>>>(x, xb, M * C / 8);
    transpose_cast_f32<<<dim3(3 * C / 64, C / 64), 256, 0, stream>>>(Wqkv, WqkvT, C, 3 * C);
    // 2) qkv = xb @ WqkvT^T
    gemm_bt<<<dim3(3 * C / 128, M / 128), 256, 0, stream>>>(xb, WqkvT, qkv, M, 3 * C, C, 0);
    // 3) V transpose (k-permuted layout) and Wout cast
    vtrans<<<dim3(T / 64, 2, B * 16), 256, 0, stream>>>(qkv, VTp);
    transpose_cast_f32<<<dim3(C / 64, C / 64), 256, 0, stream>>>(Wout, WoutT, C, C);
    // 4) flash attention
    flash_attn<<<dim3(T / 128, B * 16), 256, 0, stream>>>(qkv, VTp, O);
    // 5) out = O @ WoutT^T (fp32 out)
    gemm_bt<<<dim3(C / 128, M / 128), 256, 0, stream>>>(O, WoutT, d_out, M, C, C, 1);
}

// Round 5
// 420.819 us; speedup vs baseline: 1.2602x; 1.0019x over previous
//
#include <hip/hip_runtime.h>
#include <stdint.h>

typedef __bf16 bf16x8 __attribute__((ext_vector_type(8)));
typedef float f32x4 __attribute__((ext_vector_type(4)));
typedef unsigned short u16x8 __attribute__((ext_vector_type(8)));
typedef unsigned int u32x4 __attribute__((ext_vector_type(4)));

__device__ __forceinline__ unsigned short f2bf(float f) {
    unsigned int u = __builtin_bit_cast(unsigned int, f);
    unsigned int r = u + 0x7fffu + ((u >> 16) & 1u);
    return (unsigned short)(r >> 16);
}

// v_cvt_pk_bf16_f32: lo <- bf16(a), hi <- bf16(b)
__device__ __forceinline__ unsigned int cvt_pk_bf16(float a, float b) {
    unsigned int r;
    asm("v_cvt_pk_bf16_f32 %0, %1, %2" : "=v"(r) : "v"(a), "v"(b));
    return r;
}

// async global->LDS, 16B per lane. LDS dest = wave-uniform base + lane*16.
__device__ __forceinline__ void async16(const void* g, void* l) {
    __builtin_amdgcn_global_load_lds(
        (const __attribute__((address_space(1))) void*)g,
        (__attribute__((address_space(3))) void*)l, 16, 0, 0);
}

// ---------------------------------------------------------------------------
// x fp32 -> bf16, elementwise (8 elems/thread)
// ---------------------------------------------------------------------------
__global__ __launch_bounds__(256) void cast_bf16(
    const float* __restrict__ src, unsigned short* __restrict__ dst, int n8)
{
    int i = blockIdx.x * 256 + threadIdx.x;
    if (i >= n8) return;
    const float* f = src + (size_t)i * 8;
    f32x4 a = *reinterpret_cast<const f32x4*>(f);
    f32x4 b = *reinterpret_cast<const f32x4*>(f + 4);
    u16x8 r;
    r[0]=f2bf(a[0]); r[1]=f2bf(a[1]); r[2]=f2bf(a[2]); r[3]=f2bf(a[3]);
    r[4]=f2bf(b[0]); r[5]=f2bf(b[1]); r[6]=f2bf(b[2]); r[7]=f2bf(b[3]);
    *reinterpret_cast<u16x8*>(dst + (size_t)i * 8) = r;
}

// ---------------------------------------------------------------------------
// W fp32 [R][Cc] -> bf16 W^T [Cc][R]. 64x64 tiles, XOR-swizzled LDS
// ---------------------------------------------------------------------------
__global__ __launch_bounds__(256) void transpose_cast_f32(
    const float* __restrict__ src, unsigned short* __restrict__ dst, int R, int Cc)
{
    __shared__ unsigned short St[64 * 64];
    const int tid = threadIdx.x;
    const int r0 = blockIdx.y * 64, c0 = blockIdx.x * 64;
    const int lr  = tid >> 2;          // 0..63
    const int lcb = (tid & 3) * 16;    // 0,16,32,48
    const float* sp = src + (size_t)(r0 + lr) * Cc + c0 + lcb;
    #pragma unroll
    for (int u = 0; u < 4; u++) {
        f32x4 v = *reinterpret_cast<const f32x4*>(sp + 4 * u);
        #pragma unroll
        for (int e = 0; e < 4; e++) {
            int c = lcb + 4 * u + e;
            St[c * 64 + (((lr >> 3) ^ ((c >> 4) & 3)) << 3) + (lr & 7)] = f2bf(v[e]);
        }
    }
    __syncthreads();
    #pragma unroll
    for (int i = 0; i < 2; i++) {
        int ck = tid + 256 * i;
        int c = ck >> 3, ch = ck & 7;
        u16x8 val = *reinterpret_cast<const u16x8*>(&St[c * 64 + ((ch ^ ((c >> 4) & 3)) << 3)]);
        *reinterpret_cast<u16x8*>(dst + (size_t)(c0 + c) * R + r0 + ch * 8) = val;
    }
}

// ---------------------------------------------------------------------------
// V-part of qkv -> VT [b][h][d][t'] with per-32 t-permutation matching the
// swapped-QK^T P layout (see flash_attn).
// ---------------------------------------------------------------------------
__global__ __launch_bounds__(256) void vtrans(
    const unsigned short* __restrict__ qkv, unsigned short* __restrict__ VT)
{
    const int T = 2048, CH = 6144;
    __shared__ unsigned short St[64 * 64];
    const int tid = threadIdx.x;
    const int bh = blockIdx.z;
    const int b = bh >> 4, h = bh & 15;
    const int t0 = blockIdx.x * 64, d0 = blockIdx.y * 64;
    const int lr  = tid >> 2;
    const int lcb = (tid & 3) * 16;
    const unsigned short* sp = qkv + (size_t)(b * T + t0 + lr) * CH + 4096 + h * 128 + d0 + lcb;
    u16x8 v0 = *reinterpret_cast<const u16x8*>(sp);
    u16x8 v1 = *reinterpret_cast<const u16x8*>(sp + 8);
    #pragma unroll
    for (int e = 0; e < 8; e++) {
        int c = lcb + e;
        St[c * 64 + (((lr >> 3) ^ ((c >> 4) & 3)) << 3) + (lr & 7)] = v0[e];
        c = lcb + 8 + e;
        St[c * 64 + (((lr >> 3) ^ ((c >> 4) & 3)) << 3) + (lr & 7)] = v1[e];
    }
    __syncthreads();
    #pragma unroll
    for (int i = 0; i < 2; i++) {
        int ck = tid + 256 * i;
        int d = ck >> 3, ch = ck & 7;
        const int Q = ch & 3, B32 = ch >> 2;
        u16x8 val;
        #pragma unroll
        for (int e = 0; e < 4; e++) {
            int ta = 32 * B32 + 4 * Q + e;        // first half of chunk
            int tb = ta + 16;                     // second half
            val[e]     = St[d * 64 + (((ta >> 3) ^ ((d >> 4) & 3)) << 3) + (ta & 7)];
            val[4 + e] = St[d * 64 + (((tb >> 3) ^ ((d >> 4) & 3)) << 3) + (tb & 7)];
        }
        *reinterpret_cast<u16x8*>(VT + (size_t)(bh * 128 + d0 + d) * T + t0 + ch * 8) = val;
    }
}

// ---------------------------------------------------------------------------
// Double-buffered GEMM with single-barrier counted pipeline (round 4) + T2
// bank-conflict-free LDS swizzle (this round):
//   LDS tile As[r][k] (pitch 64B, 4 chunks of 16B per row). Fragment read
//   lane (quad,l16) previously hit chunk=quad for 16 rows -> consecutive
//   8-lane groups piled on 2 bank-groups (4-way conflict, 12.6M cycles).
//   Swizzle: chunk' = quad ^ ((l16>>1)&3). Lanes 0..7 now start at banks
//   {0,16,4,20,8,24,12,28} - all 8 groups, conflict-free.
//   Applied both-sides: LDS dest stays linear (global_load_lds requirement);
//   the GLOBAL source chunk is inverse-swizzled ((lane&3)^((lane>>3)&3) -
//   key (row>>1)&3 reduces to lane bits; invariant under +64-row offset),
//   and the read applies the same involution -> data per MFMA bit-identical
//   to the unswizzled kernel.
// ---------------------------------------------------------------------------
__global__ __launch_bounds__(256) void gemm_bt(
    const unsigned short* __restrict__ A,   // [M][K] bf16
    const unsigned short* __restrict__ BT,  // [N][K] bf16
    void* __restrict__ C, int M, int N, int K, int cF32)
{
    __shared__ unsigned short As[2][128 * 32];
    __shared__ unsigned short Bs[2][128 * 32];
    const int tid = threadIdx.x;
    const int w = tid >> 6, lane = tid & 63;
    const int quad = lane >> 4, l16 = lane & 15;
    const int wm = (w >> 1) * 64, wn = (w & 1) * 64;
    const int m0 = blockIdx.y * 128, n0 = blockIdx.x * 128;

    const int srow = w * 16 + (lane >> 2);
    const int scol = ((lane & 3) ^ ((lane >> 3) & 3)) * 8;   // inverse-swizzled source chunk
    const unsigned short* aG = A  + (size_t)(m0 + srow) * K + scol;
    const unsigned short* bG = BT + (size_t)(n0 + srow) * K + scol;
    const int ldsO = (w * 16) * 32;            // wave-uniform LDS offset

    // swizzled fragment k-chunk (elements); key uniform over i/c/wm/wn since
    // those are multiples of 16 (contribute 0 to (row>>1)&3)
    const int kch = (quad ^ ((l16 >> 1) & 3)) * 8;

    f32x4 acc[4][4] = {};
    const int nkt = K >> 5;

    // prologue: stage tile 0
    async16(aG, &As[0][ldsO]);
    async16(aG + (size_t)64 * K, &As[0][ldsO + 64 * 32]);
    async16(bG, &Bs[0][ldsO]);
    async16(bG + (size_t)64 * K, &Bs[0][ldsO + 64 * 32]);
    asm volatile("s_waitcnt vmcnt(0)\n\ts_barrier" ::: "memory");

    int ct = 0;
    for (int t = 0; t < nkt; ++t) {
        // stage next tile into the other buffer (in flight across compute)
        if (t + 1 < nkt) {
            const int k1 = (t + 1) * 32;
            async16(aG + k1, &As[ct ^ 1][ldsO]);
            async16(aG + (size_t)64 * K + k1, &As[ct ^ 1][ldsO + 64 * 32]);
            async16(bG + k1, &Bs[ct ^ 1][ldsO]);
            async16(bG + (size_t)64 * K + k1, &Bs[ct ^ 1][ldsO + 64 * 32]);
        }

        bf16x8 af[4], bf[4];
        #pragma unroll
        for (int i = 0; i < 4; i++)
            af[i] = *reinterpret_cast<const bf16x8*>(&As[ct][(wm + i * 16 + l16) * 32 + kch]);
        #pragma unroll
        for (int c = 0; c < 4; c++)
            bf[c] = *reinterpret_cast<const bf16x8*>(&Bs[ct][(wn + c * 16 + l16) * 32 + kch]);

        __builtin_amdgcn_s_setprio(1);
        #pragma unroll
        for (int i = 0; i < 4; i++)
            #pragma unroll
            for (int c = 0; c < 4; c++)
                acc[i][c] = __builtin_amdgcn_mfma_f32_16x16x32_bf16(af[i], bf[c], acc[i][c], 0, 0, 0);
        __builtin_amdgcn_s_setprio(0);

        // ds_reads retired (WAR) + prefetch landed; then cross together
        asm volatile("s_waitcnt vmcnt(0) lgkmcnt(0)\n\ts_barrier" ::: "memory");
        ct ^= 1;
    }

    #pragma unroll
    for (int i = 0; i < 4; i++)
        #pragma unroll
        for (int c = 0; c < 4; c++)
            #pragma unroll
            for (int r = 0; r < 4; r++) {
                const int row = m0 + wm + i * 16 + quad * 4 + r;
                const int col = n0 + wn + c * 16 + l16;
                const size_t off = (size_t)row * N + col;
                if (cF32) ((float*)C)[off] = acc[i][c][r];
                else ((unsigned short*)C)[off] = f2bf(acc[i][c][r]);
            }
}

// ---------------------------------------------------------------------------
// Flash attention v2 (causal), swapped-QK^T / lane-local softmax,
// double-buffered K/V staging with counted-vmcnt pipeline (round-2 version,
// unchanged — it measured well).
// ---------------------------------------------------------------------------
__global__ __launch_bounds__(256, 2) void flash_attn(
    const unsigned short* __restrict__ qkv,
    const unsigned short* __restrict__ VT,
    unsigned short* __restrict__ Out)
{
    const int T = 2048, CH = 6144;
    __shared__ unsigned short KsBuf[2][64 * 128];   // [kv][d-chunk swizzled]
    __shared__ unsigned short VtBuf[2][128 * 64];   // [d][kv'-chunk swizzled]

    const int tid = threadIdx.x;
    const int w = tid >> 6, lane = tid & 63;
    const int quad = lane >> 4, l16 = lane & 15;
    const int bh = blockIdx.y, b = bh >> 4, h = bh & 15;
    const int q0 = (gridDim.x - 1 - blockIdx.x) * 128;   // heavy blocks first

    const float sc = 0.08838834764831845f * 1.4426950408889634f;
    const float NINF = -__builtin_inff();

    // Q fragments (B-operand), scale folded in
    bf16x8 qf[2][4];
    #pragma unroll
    for (int st = 0; st < 2; st++) {
        const unsigned short* qrow = qkv + (size_t)(b * T + q0 + w * 32 + st * 16 + l16) * CH + h * 128;
        #pragma unroll
        for (int dc = 0; dc < 4; dc++) {
            u16x8 raw = *reinterpret_cast<const u16x8*>(qrow + dc * 32 + quad * 8);
            u16x8 scl;
            #pragma unroll
            for (int e = 0; e < 8; e++) {
                float f = __builtin_bit_cast(float, (unsigned int)raw[e] << 16);
                scl[e] = f2bf(f * sc);
            }
            qf[st][dc] = __builtin_bit_cast(bf16x8, scl);
        }
    }

    f32x4 o[2][8] = {};
    float m_i[2] = {NINF, NINF};
    float l_i[2] = {0.f, 0.f};
    const int xsw = l16 & 7;

    const int kRow = (lane >> 4);
    const int kCh  = lane & 15;
    const int vRow = (lane >> 3);
    const int vCh  = lane & 7;

    auto stageKV = [&](int kv0, unsigned short* kp, unsigned short* vp) {
        #pragma unroll
        for (int i = 0; i < 4; i++) {
            const int r0 = i * 16 + w * 4;
            const int kv = r0 + kRow;
            const int ch = kCh ^ (kv & 7);
            async16(qkv + (size_t)(b * T + kv0 + kv) * CH + 2048 + h * 128 + ch * 8,
                    kp + r0 * 128);
        }
        #pragma unroll
        for (int i = 0; i < 4; i++) {
            const int r0 = i * 32 + w * 8;
            const int d = r0 + vRow;
            const int ch = vCh ^ (d & 7);
            async16(VT + ((size_t)bh * 128 + d) * T + kv0 + ch * 8,
                    vp + r0 * 64);
        }
    };

    unsigned short* kc = KsBuf[0];
    unsigned short* vc = VtBuf[0];
    unsigned short* kn = KsBuf[1];
    unsigned short* vn = VtBuf[1];

    const int nt = (q0 + 128) / 64;

    stageKV(0, kc, vc);
    asm volatile("s_waitcnt vmcnt(0)\n\ts_barrier" ::: "memory");

    for (int t = 0; t < nt; ++t) {
        const int kv0 = t * 64;
        if (t + 1 < nt) stageKV((t + 1) * 64, kn, vn);

        // ---- S^T = K Q^T ----
        f32x4 s[2][4] = {};
        __builtin_amdgcn_s_setprio(1);
        #pragma unroll
        for (int dc = 0; dc < 4; dc++)
            #pragma unroll
            for (int ntt = 0; ntt < 4; ntt++) {
                bf16x8 kf = *reinterpret_cast<const bf16x8*>(
                    &kc[(ntt * 16 + l16) * 128 + (((dc * 4 + quad) ^ xsw) << 3)]);
                s[0][ntt] = __builtin_amdgcn_mfma_f32_16x16x32_bf16(kf, qf[0][dc], s[0][ntt], 0, 0, 0);
                s[1][ntt] = __builtin_amdgcn_mfma_f32_16x16x32_bf16(kf, qf[1][dc], s[1][ntt], 0, 0, 0);
            }
        __builtin_amdgcn_s_setprio(0);

        // ---- softmax, lane-local rows ----
        unsigned int pk[2][4][2];
        #pragma unroll
        for (int st = 0; st < 2; st++) {
            const int qs = q0 + w * 32 + st * 16;
            const int qrow = qs + l16;
            if (kv0 + 63 > qs) {                     // diagonal: causal mask
                #pragma unroll
                for (int ntt = 0; ntt < 4; ntt++)
                    #pragma unroll
                    for (int r = 0; r < 4; r++)
                        if (kv0 + ntt * 16 + quad * 4 + r > qrow) s[st][ntt][r] = NINF;
            }
            float mx = fmaxf(fmaxf(fmaxf(s[st][0][0], s[st][0][1]), fmaxf(s[st][0][2], s[st][0][3])),
                             fmaxf(fmaxf(s[st][1][0], s[st][1][1]), fmaxf(s[st][1][2], s[st][1][3])));
            mx = fmaxf(mx,
                 fmaxf(fmaxf(fmaxf(s[st][2][0], s[st][2][1]), fmaxf(s[st][2][2], s[st][2][3])),
                       fmaxf(fmaxf(s[st][3][0], s[st][3][1]), fmaxf(s[st][3][2], s[st][3][3]))));
            mx = fmaxf(mx, __shfl_xor(mx, 16));
            mx = fmaxf(mx, __shfl_xor(mx, 32));

            const float mold = m_i[st];
            if (!__all(mx <= mold + 8.0f)) {         // rescale (rare)
                const float mnew = fmaxf(mold, mx);
                const float alpha = exp2f(mold - mnew);
                m_i[st] = mnew;
                l_i[st] *= alpha;
                #pragma unroll
                for (int r = 0; r < 4; r++) {
                    const float a = __shfl(alpha, quad * 4 + r);
                    #pragma unroll
                    for (int c = 0; c < 8; c++) o[st][c][r] *= a;
                }
            }
            const float m = m_i[st];
            float p[4][4];
            #pragma unroll
            for (int ntt = 0; ntt < 4; ntt++)
                #pragma unroll
                for (int r = 0; r < 4; r++)
                    p[ntt][r] = exp2f(s[st][ntt][r] - m);
            float ps = ((p[0][0] + p[0][1]) + (p[0][2] + p[0][3]))
                     + ((p[1][0] + p[1][1]) + (p[1][2] + p[1][3]))
                     + ((p[2][0] + p[2][1]) + (p[2][2] + p[2][3]))
                     + ((p[3][0] + p[3][1]) + (p[3][2] + p[3][3]));
            ps += __shfl_xor(ps, 16);
            ps += __shfl_xor(ps, 32);
            l_i[st] += ps;
            #pragma unroll
            for (int ntt = 0; ntt < 4; ntt++) {
                pk[st][ntt][0] = cvt_pk_bf16(p[ntt][0], p[ntt][1]);
                pk[st][ntt][1] = cvt_pk_bf16(p[ntt][2], p[ntt][3]);
            }
        }

        // ---- O += P V ----
        __builtin_amdgcn_s_setprio(1);
        #pragma unroll
        for (int kc2 = 0; kc2 < 2; kc2++) {
            u32x4 a0, a1;
            a0[0] = pk[0][2*kc2][0];   a0[1] = pk[0][2*kc2][1];
            a0[2] = pk[0][2*kc2+1][0]; a0[3] = pk[0][2*kc2+1][1];
            a1[0] = pk[1][2*kc2][0];   a1[1] = pk[1][2*kc2][1];
            a1[2] = pk[1][2*kc2+1][0]; a1[3] = pk[1][2*kc2+1][1];
            const bf16x8 pf0 = __builtin_bit_cast(bf16x8, a0);
            const bf16x8 pf1 = __builtin_bit_cast(bf16x8, a1);
            #pragma unroll
            for (int c = 0; c < 8; c++) {
                bf16x8 vf = *reinterpret_cast<const bf16x8*>(
                    &vc[(c * 16 + l16) * 64 + (((kc2 * 4 + quad) ^ xsw) << 3)]);
                o[0][c] = __builtin_amdgcn_mfma_f32_16x16x32_bf16(pf0, vf, o[0][c], 0, 0, 0);
                o[1][c] = __builtin_amdgcn_mfma_f32_16x16x32_bf16(pf1, vf, o[1][c], 0, 0, 0);
            }
        }
        __builtin_amdgcn_s_setprio(0);

        asm volatile("s_waitcnt vmcnt(0) lgkmcnt(0)\n\ts_barrier" ::: "memory");

        unsigned short* tp;
        tp = kc; kc = kn; kn = tp;
        tp = vc; vc = vn; vn = tp;
    }

    #pragma unroll
    for (int st = 0; st < 2; st++)
        #pragma unroll
        for (int r = 0; r < 4; r++) {
            const float linv = 1.0f / __shfl(l_i[st], quad * 4 + r);
            const int row = q0 + w * 32 + st * 16 + quad * 4 + r;
            const size_t base = (size_t)(b * T + row) * 2048 + h * 128;
            #pragma unroll
            for (int c = 0; c < 8; c++)
                Out[base + c * 16 + l16] = f2bf(o[st][c][r] * linv);
        }
}

extern "C" void kernel_launch(void* const* d_in, const int* in_sizes, int n_in,
                              void* d_out, int out_size, void* d_ws, size_t ws_size,
                              hipStream_t stream) {
    const int B = 2, T = 2048, C = 2048;
    const float* x    = (const float*)d_in[0];
    const float* Wqkv = (const float*)d_in[2];   // [C][3C] fp32
    const float* Wout = (const float*)d_in[3];   // [C][C]  fp32
    const int M = B * T;                         // 4096

    char* ws = (char*)d_ws;
    unsigned short* qkv   = (unsigned short*)ws;                       // +0
    unsigned short* xb    = (unsigned short*)(ws + 50331648);          // region A
    unsigned short* WoutT = xb;
    unsigned short* WqkvT = (unsigned short*)(ws + 67108864);          // region B
    unsigned short* VTp   = WqkvT;
    unsigned short* O     = (unsigned short*)(ws + 92274688);

    // 1) casts for GEMM1
    cast_bf16<<<dim3(M * C / 8 / 256), 256, 0, stream>>>(x, xb, M * C / 8);
    transpose_cast_f32<<<dim3(3 * C / 64, C / 64), 256, 0, stream>>>(Wqkv, WqkvT, C, 3 * C);
    // 2) qkv = xb @ WqkvT^T
    gemm_bt<<<dim3(3 * C / 128, M / 128), 256, 0, stream>>>(xb, WqkvT, qkv, M, 3 * C, C, 0);
    // 3) V transpose (k-permuted layout) and Wout cast
    vtrans<<<dim3(T / 64, 2, B * 16), 256, 0, stream>>>(qkv, VTp);
    transpose_cast_f32<<<dim3(C / 64, C / 64), 256, 0, stream>>>(Wout, WoutT, C, C);
    // 4) flash attention
    flash_attn<<<dim3(T / 128, B * 16), 256, 0, stream>>>(qkv, VTp, O);
    // 5) out = O @ WoutT^T (fp32 out)
    gemm_bt<<<dim3(C / 128, M / 128), 256, 0, stream>>>(O, WoutT, d_out, M, C, C, 1);
}